// Round 10
// baseline (376.256 us; speedup 1.0000x reference)
//
#include <hip/hip_runtime.h>
#include <hip/hip_fp16.h>
#include <math.h>

// CapsuleRouting: u (8,144,16,16,12,12) f32, a (8,144,12,12) f32
// out: v (8,16,16,144) f32  ++  a_out (8,16,144) f32
//
// R9 counters: our kernels hit a ~1.6 TB/s READ ceiling regardless of access
// pattern, while writes ride along free (capsA: 162MB R + 104MB W in 100us);
// harness fills/flat copies do 6.3-6.8 TB/s. Remaining difference: they are
// flat massive-grid tiny-state streams. So pass A becomes exactly that:
//   capsA1: 1.33M threads (81 waves/CU queued), no LDS, no barriers, ~40
//   VGPR; thread = one (chunk,b,cp,f4) partial: 8 independent fully-
//   contiguous f4 loads, sum -> part store, pack -> 8 uint2 fp16 stores.
// fp16 copy layout [b][B][cp][f4] uint2 (uint2 = 4 pos as 2x half2): pack
// stores are thread-local+contiguous; capsB reads 16 uint2 per (c,f4i,jj).
// capsB/reduce structure unchanged from R9 (332.9us verified).

#define NB 8
#define BDIM 144
#define CDIM 16
#define PDIM 16
#define SDIM 144
#define NF4 (SDIM / 4)                  // 36 f4 (=uint2) per 144-pos row
#define BC 8                            // B-rows per chunk
#define WJ 2                            // B-rows per wave (capsB)
#define NBC (BDIM / BC)                 // 18 chunks
#define NPT 9                           // f4 quads per row
#define VELEMS (NB * CDIM * PDIM * SDIM)  // 294912
#define VF4 (VELEMS / 4)                // 73728
#define A1THREADS (NBC * NB * CDIM * PDIM * NF4)  // 1327104

static __device__ __forceinline__ float4 f4zero() {
  return make_float4(0.f, 0.f, 0.f, 0.f);
}
static __device__ __forceinline__ float4 f4add(float4 a, float4 b) {
  return make_float4(a.x + b.x, a.y + b.y, a.z + b.z, a.w + b.w);
}
static __device__ __forceinline__ unsigned pk16(float lo, float hi) {
  union { __half2 h; unsigned u; } v;
  v.h = __floats2half2_rn(lo, hi);  // low half = lo
  return v.u;
}
static __device__ __forceinline__ float2 upk16(unsigned x) {
  union { __half2 h; unsigned u; } v;
  v.u = x;
  return __half22float2(v.h);  // .x = low, .y = high
}

// ---- pass A (iter 0): flat stream. sum 8 B-rows + pack fp16 copy ----
__global__ __launch_bounds__(256) void capsA1(
    const float* __restrict__ u, uint2* __restrict__ u16,
    float* __restrict__ part) {
  const int o = blockIdx.x * 256 + threadIdx.x;  // (chunk,b,cp,f4) flat
  const int f4 = o % NF4;
  const int r1 = o / NF4;
  const int cp = r1 & 255;
  const int r2 = r1 >> 8;
  const int b = r2 & 7;
  const int chunk = r2 >> 3;

  const float4* ub = (const float4*)u +
                     ((size_t)(b * BDIM + chunk * BC) * 256 + cp) * NF4 + f4;
  uint2* uq = u16 + ((size_t)(b * BDIM + chunk * BC) * 256 + cp) * NF4 + f4;

  float4 v[BC];
#pragma unroll
  for (int j = 0; j < BC; ++j)
    v[j] = ub[(size_t)j * (256 * NF4)];  // 8 independent coalesced loads

  float4 s = f4zero();
#pragma unroll
  for (int j = 0; j < BC; ++j) {
    s = f4add(s, v[j]);
    uq[(size_t)j * (256 * NF4)] =
        make_uint2(pk16(v[j].x, v[j].y), pk16(v[j].z, v[j].w));
  }
  ((float4*)part)[(size_t)chunk * VF4 + (size_t)(b * 256 + cp) * NF4 + f4] =
      make_float4(s.x * (1.0f / CDIM), s.y * (1.0f / CDIM),
                  s.z * (1.0f / CDIM), s.w * (1.0f / CDIM));
}

// ---- pass B (iters 1,2): fp16 sweep, softmax-weighted partial sums ----
__global__ __launch_bounds__(256) void capsB(
    const uint2* __restrict__ u16, const float* __restrict__ a,
    const float* __restrict__ V, float* __restrict__ part) {
  __shared__ float4 comb[2][64][PDIM + 1];  // 34.8 KB

  const int tid = threadIdx.x;
  const int w = tid >> 6;
  const int lane = tid & 63;
  const int c = lane >> 2;
  const int posq = lane & 3;
  const int chunk = blockIdx.x;
  const int y = blockIdx.y;
  const int b = blockIdx.z;
  const int f4i = y * 4 + posq;
  const int B0 = chunk * BC + w * WJ;

  float4 Vr[PDIM];
  {
    const float4* vb =
        (const float4*)V + ((size_t)(b * CDIM + c) * PDIM) * NF4 + f4i;
#pragma unroll
    for (int p = 0; p < PDIM; ++p) Vr[p] = vb[p * NF4];
  }

  float4 sacc[PDIM];
#pragma unroll
  for (int p = 0; p < PDIM; ++p) sacc[p] = f4zero();

#pragma unroll
  for (int jj = 0; jj < WJ; ++jj) {
    const uint2* uq =
        u16 + ((size_t)(b * BDIM + B0 + jj) * 256 + c * PDIM) * NF4 + f4i;
    uint2 U[PDIM];
#pragma unroll
    for (int p = 0; p < PDIM; ++p) U[p] = uq[p * NF4];  // 16 independent loads

    float4 dot;
    {
      const float4 av =
          ((const float4*)(a + (size_t)(b * BDIM + B0 + jj) * SDIM))[f4i];
      dot = make_float4(av.x * (1.0f / CDIM), av.y * (1.0f / CDIM),
                        av.z * (1.0f / CDIM), av.w * (1.0f / CDIM));
    }
#pragma unroll
    for (int p = 0; p < PDIM; ++p) {
      const float2 t01 = upk16(U[p].x);  // pos 4f4+0, +1
      const float2 t23 = upk16(U[p].y);  // pos 4f4+2, +3
      dot.x = fmaf(t01.x, Vr[p].x, dot.x);
      dot.y = fmaf(t01.y, Vr[p].y, dot.y);
      dot.z = fmaf(t23.x, Vr[p].z, dot.z);
      dot.w = fmaf(t23.y, Vr[p].w, dot.w);
    }
    float4 e;  // no-max softmax: logits O(10), fp32-safe (R2-R9 verified)
    e.x = __expf(dot.x); e.y = __expf(dot.y);
    e.z = __expf(dot.z); e.w = __expf(dot.w);
    float4 se = e;  // sum over 16 c's: butterfly on lane bits 2..5
#pragma unroll
    for (int m = 4; m <= 32; m <<= 1) {
      se.x += __shfl_xor(se.x, m);
      se.y += __shfl_xor(se.y, m);
      se.z += __shfl_xor(se.z, m);
      se.w += __shfl_xor(se.w, m);
    }
    float4 w4;
    w4.x = e.x * __builtin_amdgcn_rcpf(se.x);
    w4.y = e.y * __builtin_amdgcn_rcpf(se.y);
    w4.z = e.z * __builtin_amdgcn_rcpf(se.z);
    w4.w = e.w * __builtin_amdgcn_rcpf(se.w);
#pragma unroll
    for (int p = 0; p < PDIM; ++p) {
      const float2 t01 = upk16(U[p].x);
      const float2 t23 = upk16(U[p].y);
      sacc[p].x = fmaf(w4.x, t01.x, sacc[p].x);
      sacc[p].y = fmaf(w4.y, t01.y, sacc[p].y);
      sacc[p].z = fmaf(w4.z, t23.x, sacc[p].z);
      sacc[p].w = fmaf(w4.w, t23.y, sacc[p].w);
    }
  }

  // 4-wave tree combine (R7-proven)
  if (w >= 2) {
#pragma unroll
    for (int p = 0; p < PDIM; ++p) comb[w - 2][lane][p] = sacc[p];
  }
  __syncthreads();
  if (w < 2) {
#pragma unroll
    for (int p = 0; p < PDIM; ++p) sacc[p] = f4add(sacc[p], comb[w][lane][p]);
  }
  __syncthreads();
  if (w == 1) {
#pragma unroll
    for (int p = 0; p < PDIM; ++p) comb[0][lane][p] = sacc[p];
  }
  __syncthreads();
  if (w == 0) {
    float4* sp = (float4*)part + (size_t)chunk * VF4 +
                 ((size_t)(b * CDIM + c) * PDIM) * NF4 + f4i;
#pragma unroll
    for (int p = 0; p < PDIM; ++p)
      sp[p * NF4] = f4add(sacc[p], comb[0][lane][p]);
  }
}

// ---- reduce 18 chunks, squash, update V / outputs (R7-verbatim) ----
__global__ __launch_bounds__(256) void reduce_f4(
    const float* __restrict__ part, float* __restrict__ V,
    float* __restrict__ out_v, float* __restrict__ out_a, int iter) {
  const int tid = threadIdx.x;
  const int w = tid >> 6;
  const int lane = tid & 63;
  const int p = lane >> 2;
  const int posq = lane & 3;
  const int quad = blockIdx.x;
  const int c = blockIdx.y * 4 + w;
  const int b = blockIdx.z;
  const int f4 = quad * 4 + posq;
  const size_t idx = ((size_t)((b * CDIM + c) * PDIM) + p) * NF4 + f4;

  float4 sv = f4zero();
#pragma unroll
  for (int k = 0; k < NBC; ++k)
    sv = f4add(sv, ((const float4*)part)[(size_t)k * VF4 + idx]);

  float4 sn = make_float4(sv.x * sv.x, sv.y * sv.y, sv.z * sv.z, sv.w * sv.w);
#pragma unroll
  for (int m = 4; m <= 32; m <<= 1) {  // sum over the 16 p's
    sn.x += __shfl_xor(sn.x, m);
    sn.y += __shfl_xor(sn.y, m);
    sn.z += __shfl_xor(sn.z, m);
    sn.w += __shfl_xor(sn.w, m);
  }
  float4 sc;
  sc.x = sn.x / (1.0f + sn.x) * rsqrtf(sn.x);
  sc.y = sn.y / (1.0f + sn.y) * rsqrtf(sn.y);
  sc.z = sn.z / (1.0f + sn.z) * rsqrtf(sn.z);
  sc.w = sn.w / (1.0f + sn.w) * rsqrtf(sn.w);

  float4* Vb = (float4*)V + idx;
  if (iter == 0) {
    *Vb = make_float4(sv.x * sc.x, sv.y * sc.y, sv.z * sc.z, sv.w * sc.w);
  } else if (iter == 1) {
    float4 o = *Vb;
    *Vb = make_float4(fmaf(sv.x, sc.x, o.x), fmaf(sv.y, sc.y, o.y),
                      fmaf(sv.z, sc.z, o.z), fmaf(sv.w, sc.w, o.w));
  } else {
    ((float4*)out_v)[idx] =
        make_float4(sv.x * sc.x, sv.y * sc.y, sv.z * sc.z, sv.w * sc.w);
    if (p == 0) {  // ||squash(s)|| = sn/(1+sn) per position
      ((float4*)out_a)[(size_t)(b * CDIM + c) * NF4 + f4] =
          make_float4(sn.x / (1.0f + sn.x), sn.y / (1.0f + sn.y),
                      sn.z / (1.0f + sn.z), sn.w / (1.0f + sn.w));
    }
  }
}

// ---------------- launch: 6 dispatches, no memset, no atomics ----------------

extern "C" void kernel_launch(void* const* d_in, const int* in_sizes, int n_in,
                              void* d_out, int out_size, void* d_ws, size_t ws_size,
                              hipStream_t stream) {
  const float* u = (const float*)d_in[0];
  const float* a = (const float*)d_in[1];
  float* out_v = (float*)d_out;
  float* out_a = out_v + VELEMS;

  // ws: V f32[VELEMS] | part f32[18*VELEMS] | u16 uint2[8*144*256*36] (~107 MB)
  float* V = (float*)d_ws;
  float* part = V + VELEMS;
  uint2* u16 = (uint2*)(part + (size_t)NBC * VELEMS);

  const dim3 gR(NBC, NPT, NB);  // 18 x 9 x 8, 256 thr
  const dim3 gQ(NPT, 4, NB);    // 9 x 4 x 8, 256 thr

  capsA1<<<A1THREADS / 256, 256, 0, stream>>>(u, u16, part);
  reduce_f4<<<gQ, 256, 0, stream>>>(part, V, out_v, out_a, 0);
  capsB<<<gR, 256, 0, stream>>>(u16, a, V, part);
  reduce_f4<<<gQ, 256, 0, stream>>>(part, V, out_v, out_a, 1);
  capsB<<<gR, 256, 0, stream>>>(u16, a, V, part);
  reduce_f4<<<gQ, 256, 0, stream>>>(part, V, out_v, out_a, 2);
}

// Round 11
// 359.775 us; speedup vs baseline: 1.0458x; 1.0458x over previous
//
#include <hip/hip_runtime.h>
#include <hip/hip_fp16.h>
#include <math.h>

// CapsuleRouting: u (8,144,16,16,12,12) f32, a (8,144,12,12) f32
// out: v (8,16,16,144) f32  ++  a_out (8,16,144) f32
//
// Structure = R9 (332.9us verified): capsA f32 sweep + fp16 pack, capsB x2
// fp16 sweep (u16q layout [b][B][f4][p2][c] uint4 -> 2KB-contiguous load
// groups; R10 proved 32B-run layouts cost +20us/pass), reduce x3.
// R10 change: STREAMING READS ARE NON-TEMPORAL. Evidence: all read-heavy
// dispatches cap at 0.9-1.6 TB/s (any pattern/occupancy/run length) while
// write-only fills do 6.8 TB/s at 10% occupancy and co-resident writes are
// free -> remaining suspect is line ALLOCATION on read-miss (L2+L3 install
// storm after the harness's 648MB poison flush). nt loads bypass allocation.
// V/a loads and all stores stay cached (part is read by the next dispatch).

#define NB 8
#define BDIM 144
#define CDIM 16
#define PDIM 16
#define SDIM 144
#define NF4 (SDIM / 4)                  // 36 f4 per row
#define BC 8                            // B-rows per chunk
#define WJ 2                            // B-rows per wave
#define NBC (BDIM / BC)                 // 18 chunks
#define NPT 9                           // f4 quads per row
#define UF4STRIDE ((size_t)CDIM * PDIM * NF4)  // 9216 f4 between B-rows
#define VELEMS (NB * CDIM * PDIM * SDIM)       // 294912
#define VF4 (VELEMS / 4)                // 73728

typedef float f4v __attribute__((ext_vector_type(4)));
typedef unsigned int u4v __attribute__((ext_vector_type(4)));

static __device__ __forceinline__ float4 ntld(const float4* p) {
  f4v t = __builtin_nontemporal_load((const f4v*)p);
  return make_float4(t.x, t.y, t.z, t.w);
}
static __device__ __forceinline__ uint4 ntld(const uint4* p) {
  u4v t = __builtin_nontemporal_load((const u4v*)p);
  return make_uint4(t.x, t.y, t.z, t.w);
}
static __device__ __forceinline__ float4 f4zero() {
  return make_float4(0.f, 0.f, 0.f, 0.f);
}
static __device__ __forceinline__ float4 f4add(float4 a, float4 b) {
  return make_float4(a.x + b.x, a.y + b.y, a.z + b.z, a.w + b.w);
}
static __device__ __forceinline__ unsigned pk16(float lo, float hi) {
  union { __half2 h; unsigned u; } v;
  v.h = __floats2half2_rn(lo, hi);  // low half = lo (p even), high = hi
  return v.u;
}
static __device__ __forceinline__ float2 upk16(unsigned x) {
  union { __half2 h; unsigned u; } v;
  v.u = x;
  return __half22float2(v.h);  // .x = low (p even), .y = high (p odd)
}

// ---- pass A (iter 0): f32 sweep (nt), uniform 1/C sum, pack fp16 copy ----
__global__ __launch_bounds__(256) void capsA(
    const float* __restrict__ u, uint4* __restrict__ u16q,
    float* __restrict__ part) {
  __shared__ float4 comb[2][64][PDIM + 1];  // 34.8 KB

  const int tid = threadIdx.x;
  const int w = tid >> 6;
  const int lane = tid & 63;
  const int c = lane >> 2;
  const int posq = lane & 3;
  const int chunk = blockIdx.x;
  const int y = blockIdx.y;
  const int b = blockIdx.z;
  const int f4i = y * 4 + posq;
  const int B0 = chunk * BC + w * WJ;

  const float4* ub =
      (const float4*)u + ((size_t)((b * BDIM + B0) * CDIM + c) * PDIM) * NF4 + f4i;

  float4 sacc[PDIM];
#pragma unroll
  for (int p = 0; p < PDIM; ++p) sacc[p] = f4zero();

#pragma unroll
  for (int jj = 0; jj < WJ; ++jj) {
    const float4* ubj = ub + (size_t)jj * UF4STRIDE;
    uint4* uq = u16q + ((size_t)(b * BDIM + B0 + jj) * NF4 + f4i) * (8 * CDIM) + c;
#pragma unroll
    for (int p2 = 0; p2 < 8; ++p2) {
      const float4 lo = ntld(&ubj[(2 * p2) * NF4]);
      const float4 hi = ntld(&ubj[(2 * p2 + 1) * NF4]);
      sacc[2 * p2] = f4add(sacc[2 * p2], lo);
      sacc[2 * p2 + 1] = f4add(sacc[2 * p2 + 1], hi);
      uq[p2 * CDIM] =
          make_uint4(pk16(lo.x, hi.x), pk16(lo.y, hi.y),
                     pk16(lo.z, hi.z), pk16(lo.w, hi.w));
    }
  }

  // 4-wave tree combine (R7-proven)
  if (w >= 2) {
#pragma unroll
    for (int p = 0; p < PDIM; ++p) comb[w - 2][lane][p] = sacc[p];
  }
  __syncthreads();
  if (w < 2) {
#pragma unroll
    for (int p = 0; p < PDIM; ++p) sacc[p] = f4add(sacc[p], comb[w][lane][p]);
  }
  __syncthreads();
  if (w == 1) {
#pragma unroll
    for (int p = 0; p < PDIM; ++p) comb[0][lane][p] = sacc[p];
  }
  __syncthreads();
  if (w == 0) {
    float4* sp = (float4*)part + (size_t)chunk * VF4 +
                 ((size_t)(b * CDIM + c) * PDIM) * NF4 + f4i;
#pragma unroll
    for (int p = 0; p < PDIM; ++p) {
      const float4 v = f4add(sacc[p], comb[0][lane][p]);
      sp[p * NF4] = make_float4(v.x * (1.0f / CDIM), v.y * (1.0f / CDIM),
                                v.z * (1.0f / CDIM), v.w * (1.0f / CDIM));
    }
  }
}

// ---- pass B (iters 1,2): fp16 sweep (nt), softmax-weighted partial sums ----
__global__ __launch_bounds__(256) void capsB(
    const uint4* __restrict__ u16q, const float* __restrict__ a,
    const float* __restrict__ V, float* __restrict__ part) {
  __shared__ float4 comb[2][64][PDIM + 1];

  const int tid = threadIdx.x;
  const int w = tid >> 6;
  const int lane = tid & 63;
  const int c = lane >> 2;
  const int posq = lane & 3;
  const int chunk = blockIdx.x;
  const int y = blockIdx.y;
  const int b = blockIdx.z;
  const int f4i = y * 4 + posq;
  const int B0 = chunk * BC + w * WJ;

  float4 Vr[PDIM];
  {
    const float4* vb =
        (const float4*)V + ((size_t)(b * CDIM + c) * PDIM) * NF4 + f4i;
#pragma unroll
    for (int p = 0; p < PDIM; ++p) Vr[p] = vb[p * NF4];
  }

  float4 sacc[PDIM];
#pragma unroll
  for (int p = 0; p < PDIM; ++p) sacc[p] = f4zero();

#pragma unroll
  for (int jj = 0; jj < WJ; ++jj) {
    const uint4* uq =
        u16q + ((size_t)(b * BDIM + B0 + jj) * NF4 + f4i) * (8 * CDIM) + c;
    uint4 U[8];
#pragma unroll
    for (int p2 = 0; p2 < 8; ++p2) U[p2] = ntld(&uq[p2 * CDIM]);

    float4 dot;
    {
      const float4 av =
          ((const float4*)(a + (size_t)(b * BDIM + B0 + jj) * SDIM))[f4i];
      dot = make_float4(av.x * (1.0f / CDIM), av.y * (1.0f / CDIM),
                        av.z * (1.0f / CDIM), av.w * (1.0f / CDIM));
    }
#pragma unroll
    for (int p2 = 0; p2 < 8; ++p2) {
      const float4 va = Vr[2 * p2];
      const float4 vb2 = Vr[2 * p2 + 1];
      const float2 t0 = upk16(U[p2].x);
      const float2 t1 = upk16(U[p2].y);
      const float2 t2 = upk16(U[p2].z);
      const float2 t3 = upk16(U[p2].w);
      dot.x = fmaf(t0.x, va.x, fmaf(t0.y, vb2.x, dot.x));
      dot.y = fmaf(t1.x, va.y, fmaf(t1.y, vb2.y, dot.y));
      dot.z = fmaf(t2.x, va.z, fmaf(t2.y, vb2.z, dot.z));
      dot.w = fmaf(t3.x, va.w, fmaf(t3.y, vb2.w, dot.w));
    }
    float4 e;  // no-max softmax: logits O(10), fp32-safe (R2-R9 verified)
    e.x = __expf(dot.x); e.y = __expf(dot.y);
    e.z = __expf(dot.z); e.w = __expf(dot.w);
    float4 se = e;  // sum over 16 c's: butterfly on lane bits 2..5
#pragma unroll
    for (int m = 4; m <= 32; m <<= 1) {
      se.x += __shfl_xor(se.x, m);
      se.y += __shfl_xor(se.y, m);
      se.z += __shfl_xor(se.z, m);
      se.w += __shfl_xor(se.w, m);
    }
    float4 w4;
    w4.x = e.x * __builtin_amdgcn_rcpf(se.x);
    w4.y = e.y * __builtin_amdgcn_rcpf(se.y);
    w4.z = e.z * __builtin_amdgcn_rcpf(se.z);
    w4.w = e.w * __builtin_amdgcn_rcpf(se.w);
#pragma unroll
    for (int p2 = 0; p2 < 8; ++p2) {
      float4& sa = sacc[2 * p2];
      float4& sb = sacc[2 * p2 + 1];
      const float2 t0 = upk16(U[p2].x);
      const float2 t1 = upk16(U[p2].y);
      const float2 t2 = upk16(U[p2].z);
      const float2 t3 = upk16(U[p2].w);
      sa.x = fmaf(w4.x, t0.x, sa.x); sb.x = fmaf(w4.x, t0.y, sb.x);
      sa.y = fmaf(w4.y, t1.x, sa.y); sb.y = fmaf(w4.y, t1.y, sb.y);
      sa.z = fmaf(w4.z, t2.x, sa.z); sb.z = fmaf(w4.z, t2.y, sb.z);
      sa.w = fmaf(w4.w, t3.x, sa.w); sb.w = fmaf(w4.w, t3.y, sb.w);
    }
  }

  // 4-wave tree combine (R7-proven)
  if (w >= 2) {
#pragma unroll
    for (int p = 0; p < PDIM; ++p) comb[w - 2][lane][p] = sacc[p];
  }
  __syncthreads();
  if (w < 2) {
#pragma unroll
    for (int p = 0; p < PDIM; ++p) sacc[p] = f4add(sacc[p], comb[w][lane][p]);
  }
  __syncthreads();
  if (w == 1) {
#pragma unroll
    for (int p = 0; p < PDIM; ++p) comb[0][lane][p] = sacc[p];
  }
  __syncthreads();
  if (w == 0) {
    float4* sp = (float4*)part + (size_t)chunk * VF4 +
                 ((size_t)(b * CDIM + c) * PDIM) * NF4 + f4i;
#pragma unroll
    for (int p = 0; p < PDIM; ++p)
      sp[p * NF4] = f4add(sacc[p], comb[0][lane][p]);
  }
}

// ---- reduce 18 chunks (nt), squash, update V / outputs ----
__global__ __launch_bounds__(256) void reduce_f4(
    const float* __restrict__ part, float* __restrict__ V,
    float* __restrict__ out_v, float* __restrict__ out_a, int iter) {
  const int tid = threadIdx.x;
  const int w = tid >> 6;
  const int lane = tid & 63;
  const int p = lane >> 2;
  const int posq = lane & 3;
  const int quad = blockIdx.x;
  const int c = blockIdx.y * 4 + w;
  const int b = blockIdx.z;
  const int f4 = quad * 4 + posq;
  const size_t idx = ((size_t)((b * CDIM + c) * PDIM) + p) * NF4 + f4;

  float4 sv = f4zero();
#pragma unroll
  for (int k = 0; k < NBC; ++k)
    sv = f4add(sv, ntld(&((const float4*)part)[(size_t)k * VF4 + idx]));

  float4 sn = make_float4(sv.x * sv.x, sv.y * sv.y, sv.z * sv.z, sv.w * sv.w);
#pragma unroll
  for (int m = 4; m <= 32; m <<= 1) {  // sum over the 16 p's
    sn.x += __shfl_xor(sn.x, m);
    sn.y += __shfl_xor(sn.y, m);
    sn.z += __shfl_xor(sn.z, m);
    sn.w += __shfl_xor(sn.w, m);
  }
  float4 sc;
  sc.x = sn.x / (1.0f + sn.x) * rsqrtf(sn.x);
  sc.y = sn.y / (1.0f + sn.y) * rsqrtf(sn.y);
  sc.z = sn.z / (1.0f + sn.z) * rsqrtf(sn.z);
  sc.w = sn.w / (1.0f + sn.w) * rsqrtf(sn.w);

  float4* Vb = (float4*)V + idx;
  if (iter == 0) {
    *Vb = make_float4(sv.x * sc.x, sv.y * sc.y, sv.z * sc.z, sv.w * sc.w);
  } else if (iter == 1) {
    float4 o = *Vb;
    *Vb = make_float4(fmaf(sv.x, sc.x, o.x), fmaf(sv.y, sc.y, o.y),
                      fmaf(sv.z, sc.z, o.z), fmaf(sv.w, sc.w, o.w));
  } else {
    ((float4*)out_v)[idx] =
        make_float4(sv.x * sc.x, sv.y * sc.y, sv.z * sc.z, sv.w * sc.w);
    if (p == 0) {  // ||squash(s)|| = sn/(1+sn) per position
      ((float4*)out_a)[(size_t)(b * CDIM + c) * NF4 + f4] =
          make_float4(sn.x / (1.0f + sn.x), sn.y / (1.0f + sn.y),
                      sn.z / (1.0f + sn.z), sn.w / (1.0f + sn.w));
    }
  }
}

// ---------------- launch: 6 dispatches, no memset, no atomics ----------------

extern "C" void kernel_launch(void* const* d_in, const int* in_sizes, int n_in,
                              void* d_out, int out_size, void* d_ws, size_t ws_size,
                              hipStream_t stream) {
  const float* u = (const float*)d_in[0];
  const float* a = (const float*)d_in[1];
  float* out_v = (float*)d_out;
  float* out_a = out_v + VELEMS;

  // ws: V f32[VELEMS] | part f32[18*VELEMS] | u16q uint4[8*144*4608] (~107 MB)
  float* V = (float*)d_ws;
  float* part = V + VELEMS;
  uint4* u16q = (uint4*)(part + (size_t)NBC * VELEMS);

  const dim3 gR(NBC, NPT, NB);  // 18 x 9 x 8, 256 thr
  const dim3 gQ(NPT, 4, NB);    // 9 x 4 x 8, 256 thr

  capsA<<<gR, 256, 0, stream>>>(u, u16q, part);
  reduce_f4<<<gQ, 256, 0, stream>>>(part, V, out_v, out_a, 0);
  capsB<<<gR, 256, 0, stream>>>(u16q, a, V, part);
  reduce_f4<<<gQ, 256, 0, stream>>>(part, V, out_v, out_a, 1);
  capsB<<<gR, 256, 0, stream>>>(u16q, a, V, part);
  reduce_f4<<<gQ, 256, 0, stream>>>(part, V, out_v, out_a, 2);
}